// Round 5
// baseline (20499.007 us; speedup 1.0000x reference)
//
#include <hip/hip_runtime.h>

// RNN + FC readout on MI355X — PURE-F32 recurrence path (the recurrence has
// Lyapunov amplification >~4e3 over 2048 steps: f16/bf16 intermediates decorrelate).
//
//   A: xp[B,T,H] = input @ w_ih^T + b_h   (f32 GEMM; cols 0..255 -> d_out, 256..511 -> d_ws)
//   B: h_t = tanh(xp_t + h_{t-1} @ w_hh^T) (f32; 128 blocks = 2 CUs/batch, each owns 256 rows;
//      W-half resident: 192 VGPR f32/thread + 128KB LDS; per-step 1KB h-half exchange written
//      over the just-consumed xp row of the partner's buffer, device-scope atomics + flags)
//   C: out[B,T,O] = h @ w_out^T + b_out   (f16-dot2 GEMM, f32 out in-place over d_out)
//
// ws_size >= 134,217,728 B is PROVEN (R1==R2 bit-identical across ws/dout xh placement).

typedef _Float16 f16;
typedef __attribute__((ext_vector_type(2))) _Float16 half2_t;
typedef __attribute__((ext_vector_type(4))) float float4_t;
typedef __attribute__((ext_vector_type(2))) float float2_t;

#define NIN    256
#define NHID   512
#define NOUT   256
#define NBATCH 64
#define NT     2048

#if __has_builtin(__builtin_amdgcn_fdot2)
__device__ __forceinline__ float fdot2f(half2_t a, half2_t b, float c) {
  return __builtin_amdgcn_fdot2(a, b, c, false);   // v_dot2_f32_f16 (phase C only)
}
#else
__device__ __forceinline__ float fdot2f(half2_t a, half2_t b, float c) {
  return c + (float)a.x * (float)b.x + (float)a.y * (float)b.y;
}
#endif

__device__ int g_fx[128];   // xp rows consumed (per block)
__device__ int g_fh[128];   // h rows published (per block)

__global__ __launch_bounds__(128) void k_zero() {
  int t = threadIdx.x;
  if (t < 128) { g_fx[t] = 0; g_fh[t] = 0; }
}

// ---------------- Phase A: in-projection GEMM, full f32 ----------------
// tile M=32 x N=512 x K=256; K-chunk 8. 256 thr: mthr=t&3 (8 rows), nthr=t>>2 (8 n).
__global__ __launch_bounds__(256) void k_inproj(
    const float* __restrict__ x, const float* __restrict__ w,
    const float* __restrict__ bias, float* __restrict__ xplo, float* __restrict__ xphi)
{
  __shared__ float xs[32][260];    // 32x256 f32 (+pad4: 1040B rows, 16B-aligned)
  __shared__ float wsT[8][520];    // k-chunk 8 x n 512 (+pad8: 2080B rows, 16B-aligned)
  const int t = threadIdx.x;
  const int m0 = blockIdx.x * 32;
  const int mthr = t & 3;
  const int nthr = t >> 2;

  #pragma unroll
  for (int r = 0; r < 8; ++r) {                       // stage x tile (32x256 f32)
    int f = (t + 256 * r) * 4;
    int row = f >> 8, col = f & 255;
    *(float4_t*)&xs[row][col] =
        *reinterpret_cast<const float4_t*>(x + (size_t)(m0 + row) * NIN + col);
  }

  float acc[8][8];
  #pragma unroll
  for (int nn = 0; nn < 8; ++nn) {
    float bv = bias[nthr * 8 + nn];
    #pragma unroll
    for (int mm = 0; mm < 8; ++mm) acc[nn][mm] = bv;
  }

  for (int kc = 0; kc < 32; ++kc) {
    __syncthreads();
    #pragma unroll
    for (int r = 0; r < 4; ++r) {                     // stage w chunk (512 x 8), transposed
      int f = (t + 256 * r) * 4;
      int n = f >> 3, k0 = f & 7;
      float4_t v = *reinterpret_cast<const float4_t*>(w + (size_t)n * NIN + kc * 8 + k0);
      #pragma unroll
      for (int j = 0; j < 4; ++j) wsT[k0 + j][n] = v[j];
    }
    __syncthreads();
    #pragma unroll
    for (int kp = 0; kp < 8; ++kp) {
      float4_t wv0 = *(const float4_t*)&wsT[kp][nthr * 8];
      float4_t wv1 = *(const float4_t*)&wsT[kp][nthr * 8 + 4];
      #pragma unroll
      for (int mm = 0; mm < 8; ++mm) {
        float xv = xs[mthr * 8 + mm][kc * 8 + kp];
        acc[0][mm] = fmaf(wv0.x, xv, acc[0][mm]);
        acc[1][mm] = fmaf(wv0.y, xv, acc[1][mm]);
        acc[2][mm] = fmaf(wv0.z, xv, acc[2][mm]);
        acc[3][mm] = fmaf(wv0.w, xv, acc[3][mm]);
        acc[4][mm] = fmaf(wv1.x, xv, acc[4][mm]);
        acc[5][mm] = fmaf(wv1.y, xv, acc[5][mm]);
        acc[6][mm] = fmaf(wv1.z, xv, acc[6][mm]);
        acc[7][mm] = fmaf(wv1.w, xv, acc[7][mm]);
      }
    }
  }

  const int n0 = nthr * 8;                            // whole 8-range within one half
  float* dst = (n0 < 256) ? (xplo + n0) : (xphi + (n0 - 256));
  #pragma unroll
  for (int mm = 0; mm < 8; ++mm) {
    int m = m0 + mthr * 8 + mm;
    float4_t o0 = {acc[0][mm], acc[1][mm], acc[2][mm], acc[3][mm]};
    float4_t o1 = {acc[4][mm], acc[5][mm], acc[6][mm], acc[7][mm]};
    *reinterpret_cast<float4_t*>(dst + (size_t)m * 256)     = o0;
    *reinterpret_cast<float4_t*>(dst + (size_t)m * 256 + 4) = o1;
  }
}

// ---------------- Phase B: f32 recurrence, 2 CUs per batch ----------------
// block g: batch b=g&63, half=g>>6 owns rows [half*256, half*256+256).
// t: ks=t>>7 (k-slice of 64 within each half, wave-uniform), js=t&127 (2 rows).
// W regs: rows r0(kA,kB), r1(kA) = 48 float4 = 192 VGPR. LDS lw2: r1(kB) 128KB.
// h dbuf f32 in LDS; partial sums reduced via pacc LDS; per-step exchange:
//   my h-half -> partner's xp buffer row s (after partner consumed it: g_fx),
//   partner h-half read (device-scope) after its g_fh.
__global__ __launch_bounds__(512, 2) void k_recur(
    const float* __restrict__ whh, float* outbuf, float* wsbuf)
{
  extern __shared__ __align__(16) char smem[];
  float4_t* lw2 = (float4_t*)smem;                       // [16][512] float4 = 128KB
  float* hb   = (float*)(smem + 131072);                 // [2][512] f32
  float* pacc = (float*)(smem + 131072 + 4096);          // [4][256] f32

  const int g = blockIdx.x, p = g ^ 64;
  const int half = g >> 6, b = g & 63;
  const int t = threadIdx.x;
  const int ks = t >> 7, js = t & 127;
  const int r0 = half * 256 + js * 2, r1 = r0 + 1;
  const int kA = half * 256 + ks * 64;                   // own-half k range
  const int kB = (1 - half) * 256 + ks * 64;             // partner-half k range
  float* bufOwn   = (half ? wsbuf : outbuf) + (size_t)b * NT * 256;
  float* bufOther = (half ? outbuf : wsbuf) + (size_t)b * NT * 256;

  float4_t wr0A[16], wr0B[16], wr1A[16];
  #pragma unroll
  for (int i = 0; i < 16; ++i) {
    wr0A[i] = *reinterpret_cast<const float4_t*>(whh + (size_t)r0 * NHID + kA + i * 4);
    wr0B[i] = *reinterpret_cast<const float4_t*>(whh + (size_t)r0 * NHID + kB + i * 4);
    wr1A[i] = *reinterpret_cast<const float4_t*>(whh + (size_t)r1 * NHID + kA + i * 4);
    lw2[i * 512 + t] = *reinterpret_cast<const float4_t*>(whh + (size_t)r1 * NHID + kB + i * 4);
  }
  hb[t] = 0.0f;                                          // h_{-1} = 0 (buffer cur=0)
  __syncthreads();

  for (int s = 0; s < NT; ++s) {
    const int cur = s & 1, nxt = cur ^ 1;
    float xpv = 0.0f;
    if (t < 256) xpv = bufOwn[(size_t)s * 256 + t];      // plain load; drained at barrier A

    if (t < 64 && s > 0) {                               // wave0: fetch partner h_{s-1}
      while (__hip_atomic_load(&g_fh[p], __ATOMIC_ACQUIRE, __HIP_MEMORY_SCOPE_AGENT) < s) {}
      #pragma unroll
      for (int j = 0; j < 4; ++j) {
        float v = __hip_atomic_load(&bufOwn[(size_t)(s - 1) * 256 + t + j * 64],
                                    __ATOMIC_RELAXED, __HIP_MEMORY_SCOPE_AGENT);
        hb[cur * 512 + (1 - half) * 256 + t + j * 64] = v;
      }
    }

    float4_t a0 = {0.f, 0.f, 0.f, 0.f}, a1 = {0.f, 0.f, 0.f, 0.f};
    #pragma unroll
    for (int i = 0; i < 16; ++i) {                       // phase 1: own-half k (all-reg)
      float4_t hv = *(const float4_t*)&hb[cur * 512 + kA + i * 4];  // wave-uniform bcast
      a0 += wr0A[i] * hv;
      a1 += wr1A[i] * hv;
    }
    __syncthreads();                                     // A: partner-h in hb; xp drained
    if (t == 0)
      __hip_atomic_store(&g_fx[g], s + 1, __ATOMIC_RELEASE, __HIP_MEMORY_SCOPE_AGENT);

    #pragma unroll
    for (int i = 0; i < 16; ++i) {                       // phase 2: partner-half k
      float4_t hv = *(const float4_t*)&hb[cur * 512 + kB + i * 4];
      a0 += wr0B[i] * hv;
      a1 += lw2[i * 512 + t] * hv;
    }
    float s0 = (a0.x + a0.y) + (a0.z + a0.w);
    float s1 = (a1.x + a1.y) + (a1.z + a1.w);
    *(float2_t*)&pacc[ks * 256 + js * 2] = float2_t{s0, s1};
    __syncthreads();                                     // B: pacc complete

    if (t < 256) {
      float sum = ((pacc[t] + pacc[256 + t]) + (pacc[512 + t] + pacc[768 + t])) + xpv;
      float h = tanhf(sum);
      hb[nxt * 512 + half * 256 + t] = h;
      while (__hip_atomic_load(&g_fx[p], __ATOMIC_ACQUIRE, __HIP_MEMORY_SCOPE_AGENT) < s + 1) {}
      __hip_atomic_store(&bufOther[(size_t)s * 256 + t], h,
                         __ATOMIC_RELAXED, __HIP_MEMORY_SCOPE_AGENT);
    }
    __syncthreads();                                     // C: h stores drained; hb[nxt] ready
    if (t == 0)
      __hip_atomic_store(&g_fh[g], s + 1, __ATOMIC_RELEASE, __HIP_MEMORY_SCOPE_AGENT);
  }
}

// ---------------- Phase C: out-projection (f16 dot2, f32 out, in-place) ----------------
// h[k<256] f32 from d_ws row, h[k>=256] f32 from d_out row; y overwrites d_out row.
__global__ __launch_bounds__(256) void k_outproj(
    const float* hlo, const float* hhi, const float* __restrict__ w,
    const float* __restrict__ bias, float* out)
{
  __shared__ half2_t xs[32][258];
  __shared__ half2_t ws[256][19];
  const int t = threadIdx.x;
  const int m0 = blockIdx.x * 32;
  const int nthr = t >> 2;
  const int mthr = t & 3;

  #pragma unroll
  for (int r = 0; r < 16; ++r) {                        // stage 32x512 h (f32 -> f16)
    int f = (t + 256 * r) * 4;
    int row = f >> 9, col = f & 511;
    const float* src = (col < 256) ? (hlo + (size_t)(m0 + row) * 256 + col)
                                   : (hhi + (size_t)(m0 + row) * 256 + (col - 256));
    float4_t v = *reinterpret_cast<const float4_t*>(src);
    xs[row][(col >> 1)]     = half2_t{(f16)v.x, (f16)v.y};
    xs[row][(col >> 1) + 1] = half2_t{(f16)v.z, (f16)v.w};
  }

  float acc[4][8];
  #pragma unroll
  for (int nn = 0; nn < 4; ++nn) {
    float bv = bias[nthr * 4 + nn];
    #pragma unroll
    for (int mm = 0; mm < 8; ++mm) acc[nn][mm] = bv;
  }

  for (int kc = 0; kc < 16; ++kc) {
    __syncthreads();
    #pragma unroll
    for (int r = 0; r < 8; ++r) {                       // stage 256x32 w_out (f32 -> f16)
      int f = (t + 256 * r) * 4;
      int row = f >> 5, col = f & 31;
      float4_t v = *reinterpret_cast<const float4_t*>(w + (size_t)row * NHID + kc * 32 + col);
      ws[row][(col >> 1)]     = half2_t{(f16)v.x, (f16)v.y};
      ws[row][(col >> 1) + 1] = half2_t{(f16)v.z, (f16)v.w};
    }
    __syncthreads();
    #pragma unroll
    for (int kp = 0; kp < 16; ++kp) {
      half2_t wv[4], xv[8];
      #pragma unroll
      for (int nn = 0; nn < 4; ++nn) wv[nn] = ws[nthr * 4 + nn][kp];
      #pragma unroll
      for (int mm = 0; mm < 8; ++mm) xv[mm] = xs[mthr * 8 + mm][kc * 16 + kp];
      #pragma unroll
      for (int nn = 0; nn < 4; ++nn)
        #pragma unroll
        for (int mm = 0; mm < 8; ++mm)
          acc[nn][mm] = fdot2f(wv[nn], xv[mm], acc[nn][mm]);
    }
  }

  #pragma unroll
  for (int mm = 0; mm < 8; ++mm) {
    int m = m0 + mthr * 8 + mm;
    float4_t o = {acc[0][mm], acc[1][mm], acc[2][mm], acc[3][mm]};
    *reinterpret_cast<float4_t*>(out + (size_t)m * NOUT + nthr * 4) = o;
  }
}

extern "C" void kernel_launch(void* const* d_in, const int* in_sizes, int n_in,
                              void* d_out, int out_size, void* d_ws, size_t ws_size,
                              hipStream_t stream) {
  (void)in_sizes; (void)n_in; (void)ws_size; (void)out_size;
  const float* x     = (const float*)d_in[0];
  const float* w_ih  = (const float*)d_in[1];
  const float* w_hh  = (const float*)d_in[2];
  const float* b_h   = (const float*)d_in[3];
  const float* w_out = (const float*)d_in[4];
  const float* b_out = (const float*)d_in[5];

  float* outb = (float*)d_out;   // xp cols 0..255  -> h[256:512] -> y   (134MB)
  float* wsb  = (float*)d_ws;    // xp cols 256..511 -> h[0:256]          (134MB, proven)

  const int SMEM = 131072 + 4096 + 4096;   // lw2 + hb + pacc = 139,264 B
  (void)hipFuncSetAttribute((const void*)k_recur,
                            hipFuncAttributeMaxDynamicSharedMemorySize, SMEM);

  k_zero   <<<1, 128, 0, stream>>>();
  k_inproj <<<(NBATCH * NT) / 32, 256, 0, stream>>>(x, w_ih, b_h, outb, wsb);
  k_recur  <<<128, 512, SMEM, stream>>>(w_hh, outb, wsb);
  k_outproj<<<(NBATCH * NT) / 32, 256, 0, stream>>>(wsb, outb, w_out, b_out, outb);
}

// Round 6
// 8263.836 us; speedup vs baseline: 2.4806x; 2.4806x over previous
//
#include <hip/hip_runtime.h>

// RNN + FC readout on MI355X — pure-f32 recurrence (proven R5), optimized phase B.
//   A: xp[B,T,H] = input @ w_ih^T + b_h   (f32 GEMM; cols 0..255 -> d_out, 256..511 -> d_ws)
//   B: h_t = tanh(xp_t + h_{t-1} @ w_hh^T): 128 blocks (2 per batch) x 256 thr.
//      W-half FULLY resident: 384 f32/thread in VGPR (96 float4) + 128 f32/thread in LDS.
//      Handshake: relaxed agent atomics, padded flags, depth-2 xp prefetch (no back-pressure
//      wait), one-time startup guard. Own-half FMAs overlap partner latency.
//   C: out[B,T,O] = h @ w_out^T + b_out   (f16-dot2 GEMM, f32 in-place over d_out)

typedef _Float16 f16;
typedef __attribute__((ext_vector_type(2))) _Float16 half2_t;
typedef __attribute__((ext_vector_type(4))) float float4_t;
typedef __attribute__((ext_vector_type(2))) float float2_t;

#define NIN    256
#define NHID   512
#define NOUT   256
#define NBATCH 64
#define NT     2048

#define FL4(p) (*reinterpret_cast<const float4_t*>(p))
#define LOAD_REL(p)     __hip_atomic_load((p), __ATOMIC_RELAXED, __HIP_MEMORY_SCOPE_AGENT)
#define STORE_REL(p, v) __hip_atomic_store((p), (v), __ATOMIC_RELAXED, __HIP_MEMORY_SCOPE_AGENT)

#if __has_builtin(__builtin_amdgcn_fdot2)
__device__ __forceinline__ float fdot2f(half2_t a, half2_t b, float c) {
  return __builtin_amdgcn_fdot2(a, b, c, false);   // v_dot2_f32_f16 (phase C only)
}
#else
__device__ __forceinline__ float fdot2f(half2_t a, half2_t b, float c) {
  return c + (float)a.x * (float)b.x + (float)a.y * (float)b.y;
}
#endif

__device__ __align__(64) int g_fh[128 * 16];   // per-block step flag, 64B-spaced
__device__ __align__(64) int g_rdy[128 * 16];  // per-block prologue-done flag

__global__ __launch_bounds__(256) void k_zero() {
  int t = threadIdx.x;
  for (int i = t; i < 128 * 16; i += 256) { g_fh[i] = 0; g_rdy[i] = 0; }
}

// ---------------- Phase A: in-projection GEMM, full f32 (unchanged from R5) ----------------
__global__ __launch_bounds__(256) void k_inproj(
    const float* __restrict__ x, const float* __restrict__ w,
    const float* __restrict__ bias, float* __restrict__ xplo, float* __restrict__ xphi)
{
  __shared__ float xs[32][260];
  __shared__ float wsT[8][520];
  const int t = threadIdx.x;
  const int m0 = blockIdx.x * 32;
  const int mthr = t & 3;
  const int nthr = t >> 2;

  #pragma unroll
  for (int r = 0; r < 8; ++r) {
    int f = (t + 256 * r) * 4;
    int row = f >> 8, col = f & 255;
    *(float4_t*)&xs[row][col] =
        *reinterpret_cast<const float4_t*>(x + (size_t)(m0 + row) * NIN + col);
  }

  float acc[8][8];
  #pragma unroll
  for (int nn = 0; nn < 8; ++nn) {
    float bv = bias[nthr * 8 + nn];
    #pragma unroll
    for (int mm = 0; mm < 8; ++mm) acc[nn][mm] = bv;
  }

  for (int kc = 0; kc < 32; ++kc) {
    __syncthreads();
    #pragma unroll
    for (int r = 0; r < 4; ++r) {
      int f = (t + 256 * r) * 4;
      int n = f >> 3, k0 = f & 7;
      float4_t v = *reinterpret_cast<const float4_t*>(w + (size_t)n * NIN + kc * 8 + k0);
      #pragma unroll
      for (int j = 0; j < 4; ++j) wsT[k0 + j][n] = v[j];
    }
    __syncthreads();
    #pragma unroll
    for (int kp = 0; kp < 8; ++kp) {
      float4_t wv0 = *(const float4_t*)&wsT[kp][nthr * 8];
      float4_t wv1 = *(const float4_t*)&wsT[kp][nthr * 8 + 4];
      #pragma unroll
      for (int mm = 0; mm < 8; ++mm) {
        float xv = xs[mthr * 8 + mm][kc * 8 + kp];
        acc[0][mm] = fmaf(wv0.x, xv, acc[0][mm]);
        acc[1][mm] = fmaf(wv0.y, xv, acc[1][mm]);
        acc[2][mm] = fmaf(wv0.z, xv, acc[2][mm]);
        acc[3][mm] = fmaf(wv0.w, xv, acc[3][mm]);
        acc[4][mm] = fmaf(wv1.x, xv, acc[4][mm]);
        acc[5][mm] = fmaf(wv1.y, xv, acc[5][mm]);
        acc[6][mm] = fmaf(wv1.z, xv, acc[6][mm]);
        acc[7][mm] = fmaf(wv1.w, xv, acc[7][mm]);
      }
    }
  }

  const int n0 = nthr * 8;
  float* dst = (n0 < 256) ? (xplo + n0) : (xphi + (n0 - 256));
  #pragma unroll
  for (int mm = 0; mm < 8; ++mm) {
    int m = m0 + mthr * 8 + mm;
    float4_t o0 = {acc[0][mm], acc[1][mm], acc[2][mm], acc[3][mm]};
    float4_t o1 = {acc[4][mm], acc[5][mm], acc[6][mm], acc[7][mm]};
    *reinterpret_cast<float4_t*>(dst + (size_t)m * 256)     = o0;
    *reinterpret_cast<float4_t*>(dst + (size_t)m * 256 + 4) = o1;
  }
}

// ---------------- Phase B: f32 recurrence, weights truly resident ----------------
// block g: batch b=g&63, half=g>>6 owns global rows [half*256, +256).
// thread t: js=t&127, kk=t>>7. Rows r0=half*256+js*2, r1=r0+1.
// K split: K_own=[half*256+kk*128,+128), K_par=[(1-half)*256+kk*128,+128).
// VGPR: W[r0][K_own], W[r0][K_par], W[r1][K_own] = 96 float4 = 384 regs.
// LDS:  W[r1][K_par] interleaved lw[i*256+t] (conflict-free b128 reads).
__global__ __launch_bounds__(256, 1) void k_recur(
    const float* __restrict__ whh, float* outbuf, float* wsbuf)
{
  extern __shared__ __align__(16) char smem[];
  float4_t* lw = (float4_t*)smem;                  // 32*256 float4 = 131072 B
  float* hb    = (float*)(smem + 131072);          // [2][512] f32
  float* pacc  = (float*)(smem + 131072 + 4096);   // [2][256] f32

  const int g = blockIdx.x, p = g ^ 64;
  const int half = g >> 6, b = g & 63;
  const int t = threadIdx.x;
  const int js = t & 127, kk = t >> 7;
  const int r0 = half * 256 + js * 2, r1 = r0 + 1;
  const int ko = half * 256 + kk * 128;
  const int kp = (1 - half) * 256 + kk * 128;
  float* bufOwn   = (half ? wsbuf : outbuf) + (size_t)b * NT * 256;
  float* bufOther = (half ? outbuf : wsbuf) + (size_t)b * NT * 256;

  float4_t w0o[32], w0p[32], w1o[32];
  #pragma unroll
  for (int i = 0; i < 32; ++i) {
    w0o[i] = FL4(whh + (size_t)r0 * NHID + ko + i * 4);
    w0p[i] = FL4(whh + (size_t)r0 * NHID + kp + i * 4);
    w1o[i] = FL4(whh + (size_t)r1 * NHID + ko + i * 4);
    lw[i * 256 + t] = FL4(whh + (size_t)r1 * NHID + kp + i * 4);
  }
  hb[t] = 0.0f; hb[256 + t] = 0.0f;                // h_{-1} = 0

  // depth-2 xp prefetch queue (atomic loads bypass caches; rows 0,1 safe: partner's
  // first publish into our buffer is gated by g_rdy below)
  float xq0 = LOAD_REL(bufOwn + t);
  float xq1 = LOAD_REL(bufOwn + 256 + t);
  __syncthreads();                                 // drains prologue loads + lw/hb init
  if (t == 0) STORE_REL(&g_rdy[g * 16], 1);

  int fseen = 0;
  for (int s = 0; s < NT; ++s) {
    float* hc = hb + (s & 1) * 512;
    float* hn = hb + ((s & 1) ^ 1) * 512;

    // phase 1: own-half k (h available from previous finalize) — overlaps partner latency
    float4_t a0 = {0.f, 0.f, 0.f, 0.f}, a1 = {0.f, 0.f, 0.f, 0.f};
    #pragma unroll
    for (int i = 0; i < 32; ++i) {
      float4_t hv = *(const float4_t*)&hc[ko + i * 4];
      a0 += w0o[i] * hv;
      a1 += w1o[i] * hv;
    }

    if (s > 0) {                                   // arrival: partner h_{s-1}
      if (t == 0) {
        while (fseen < s) fseen = LOAD_REL(&g_fh[p * 16]);
      }
      __syncthreads();                             // all threads past poll
      float ph = LOAD_REL(bufOwn + (size_t)(s - 1) * 256 + t);
      hc[(1 - half) * 256 + t] = ph;
      __syncthreads();                             // partner-half in LDS
    }

    // phase 2: partner-half k
    #pragma unroll
    for (int i = 0; i < 32; ++i) {
      float4_t hv = *(const float4_t*)&hc[kp + i * 4];
      a0 += w0p[i] * hv;
      a1 += lw[i * 256 + t] * hv;
    }
    float s0 = (a0.x + a0.y) + (a0.z + a0.w);
    float s1 = (a1.x + a1.y) + (a1.z + a1.w);
    *(float2_t*)&pacc[kk * 256 + js * 2] = float2_t{s0, s1};
    __syncthreads();                               // pacc complete

    if (s == 0) {                                  // one-time: partner prologue done
      if (t == 0) { while (!LOAD_REL(&g_rdy[p * 16])) {} }
      __syncthreads();
    }

    // finalize: thread t owns local row t (global half*256+t)
    float h = tanhf(pacc[t] + pacc[256 + t] + xq0);
    hn[half * 256 + t] = h;
    STORE_REL(bufOther + (size_t)s * 256 + t, h);  // publish to partner + phase C
    xq0 = xq1;
    if (s + 2 < NT) xq1 = LOAD_REL(bufOwn + (size_t)(s + 2) * 256 + t);
    __syncthreads();                               // drains publish (all waves) + hn ready
    if (t == 0) STORE_REL(&g_fh[g * 16], s + 1);
  }
}

// ---------------- Phase C: out-projection (f16 dot2, f32 out, in-place; unchanged) ---------
__global__ __launch_bounds__(256) void k_outproj(
    const float* hlo, const float* hhi, const float* __restrict__ w,
    const float* __restrict__ bias, float* out)
{
  __shared__ half2_t xs[32][258];
  __shared__ half2_t ws[256][19];
  const int t = threadIdx.x;
  const int m0 = blockIdx.x * 32;
  const int nthr = t >> 2;
  const int mthr = t & 3;

  #pragma unroll
  for (int r = 0; r < 16; ++r) {
    int f = (t + 256 * r) * 4;
    int row = f >> 9, col = f & 511;
    const float* src = (col < 256) ? (hlo + (size_t)(m0 + row) * 256 + col)
                                   : (hhi + (size_t)(m0 + row) * 256 + (col - 256));
    float4_t v = *reinterpret_cast<const float4_t*>(src);
    xs[row][(col >> 1)]     = half2_t{(f16)v.x, (f16)v.y};
    xs[row][(col >> 1) + 1] = half2_t{(f16)v.z, (f16)v.w};
  }

  float acc[4][8];
  #pragma unroll
  for (int nn = 0; nn < 4; ++nn) {
    float bv = bias[nthr * 4 + nn];
    #pragma unroll
    for (int mm = 0; mm < 8; ++mm) acc[nn][mm] = bv;
  }

  for (int kc = 0; kc < 16; ++kc) {
    __syncthreads();
    #pragma unroll
    for (int r = 0; r < 8; ++r) {
      int f = (t + 256 * r) * 4;
      int row = f >> 5, col = f & 31;
      float4_t v = *reinterpret_cast<const float4_t*>(w + (size_t)row * NHID + kc * 32 + col);
      ws[row][(col >> 1)]     = half2_t{(f16)v.x, (f16)v.y};
      ws[row][(col >> 1) + 1] = half2_t{(f16)v.z, (f16)v.w};
    }
    __syncthreads();
    #pragma unroll
    for (int kp = 0; kp < 16; ++kp) {
      half2_t wv[4], xv[8];
      #pragma unroll
      for (int nn = 0; nn < 4; ++nn) wv[nn] = ws[nthr * 4 + nn][kp];
      #pragma unroll
      for (int mm = 0; mm < 8; ++mm) xv[mm] = xs[mthr * 8 + mm][kc * 16 + kp];
      #pragma unroll
      for (int nn = 0; nn < 4; ++nn)
        #pragma unroll
        for (int mm = 0; mm < 8; ++mm)
          acc[nn][mm] = fdot2f(wv[nn], xv[mm], acc[nn][mm]);
    }
  }

  #pragma unroll
  for (int mm = 0; mm < 8; ++mm) {
    int m = m0 + mthr * 8 + mm;
    float4_t o = {acc[0][mm], acc[1][mm], acc[2][mm], acc[3][mm]};
    *reinterpret_cast<float4_t*>(out + (size_t)m * NOUT + nthr * 4) = o;
  }
}

extern "C" void kernel_launch(void* const* d_in, const int* in_sizes, int n_in,
                              void* d_out, int out_size, void* d_ws, size_t ws_size,
                              hipStream_t stream) {
  (void)in_sizes; (void)n_in; (void)ws_size; (void)out_size;
  const float* x     = (const float*)d_in[0];
  const float* w_ih  = (const float*)d_in[1];
  const float* w_hh  = (const float*)d_in[2];
  const float* b_h   = (const float*)d_in[3];
  const float* w_out = (const float*)d_in[4];
  const float* b_out = (const float*)d_in[5];

  float* outb = (float*)d_out;   // xp cols 0..255  -> h[256:512] -> y   (134 MB)
  float* wsb  = (float*)d_ws;    // xp cols 256..511 -> h[0:256]         (134 MB, proven)

  const int SMEM = 131072 + 4096 + 2048;   // lw + hb + pacc = 137,216 B
  (void)hipFuncSetAttribute((const void*)k_recur,
                            hipFuncAttributeMaxDynamicSharedMemorySize, SMEM);

  k_zero   <<<1, 256, 0, stream>>>();
  k_inproj <<<(NBATCH * NT) / 32, 256, 0, stream>>>(x, w_ih, b_h, outb, wsb);
  k_recur  <<<128, 256, SMEM, stream>>>(w_hh, outb, wsb);
  k_outproj<<<(NBATCH * NT) / 32, 256, 0, stream>>>(wsb, outb, w_out, b_out, outb);
}

// Round 9
// 4674.569 us; speedup vs baseline: 4.3852x; 1.7678x over previous
//
#include <hip/hip_runtime.h>

// RNN + FC readout on MI355X — f32 recurrence, quarter-split, R6-PROVEN exchange protocol.
//   A: xp[B,T,H] = input @ w_ih^T + b_h   (f32 GEMM; cols 0..255 -> d_out, 256..511 -> d_ws)
//   B: h_t = tanh(xp_t + h_{t-1} @ w_hh^T): 256 blocks = 4/batch; each block owns 128 rows,
//      W all-VGPR (128 f32/thread, no spill). Exchange = R6's proven pattern: relaxed agent
//      value stores -> __syncthreads (vmcnt0 drain) -> flag store; reader polls flag ->
//      barrier -> relaxed value loads. Dedicated dbuf g_hpub (no back-pressure flag needed:
//      overwrite of slot s&1 at step s+2 is causally after all peers read it at step s+1).
//   C: out[B,T,O] = h @ w_out^T + b_out   (f16-dot2 GEMM, f32 in-place over d_out)
//
// f16 in the recurrence refuted (R7: 1.06). R8's tagged-u64/DPP-ror/SWZ variant refuted
// (0.889) — reverted to the R6-proven protocol; only the split factor (2->4) is kept.

typedef _Float16 f16;
typedef __attribute__((ext_vector_type(2))) _Float16 half2_t;
typedef __attribute__((ext_vector_type(4))) float float4_t;

#define NIN    256
#define NHID   512
#define NOUT   256
#define NBATCH 64
#define NT     2048

#define FL4(p) (*reinterpret_cast<const float4_t*>(p))
#define LOADA(p)     __hip_atomic_load((p), __ATOMIC_RELAXED, __HIP_MEMORY_SCOPE_AGENT)
#define STOREA(p, v) __hip_atomic_store((p), (v), __ATOMIC_RELAXED, __HIP_MEMORY_SCOPE_AGENT)

#if __has_builtin(__builtin_amdgcn_fdot2)
__device__ __forceinline__ float fdot2f(half2_t a, half2_t b, float c) {
  return __builtin_amdgcn_fdot2(a, b, c, false);   // v_dot2_f32_f16 (phase C only)
}
#else
__device__ __forceinline__ float fdot2f(half2_t a, half2_t b, float c) {
  return c + (float)a.x * (float)b.x + (float)a.y * (float)b.y;
}
#endif

__device__ float g_hpub[NBATCH][2][NHID];           // h exchange, dbuf by step parity (256 KB)
__device__ __align__(64) int g_flag[NBATCH * 64];   // flag[b*64 + q*16], 64B-padded

__global__ __launch_bounds__(256) void k_zero() {
  g_flag[blockIdx.x * 256 + threadIdx.x] = 0;       // grid 16 -> 4096 ints
}

// ---------------- Phase A: in-projection GEMM, full f32 (proven R5/R6) ----------------
__global__ __launch_bounds__(256) void k_inproj(
    const float* __restrict__ x, const float* __restrict__ w,
    const float* __restrict__ bias, float* __restrict__ xplo, float* __restrict__ xphi)
{
  __shared__ float xs[32][260];
  __shared__ float wsT[8][520];
  const int t = threadIdx.x;
  const int m0 = blockIdx.x * 32;
  const int mthr = t & 3;
  const int nthr = t >> 2;

  #pragma unroll
  for (int r = 0; r < 8; ++r) {
    int f = (t + 256 * r) * 4;
    int row = f >> 8, col = f & 255;
    *(float4_t*)&xs[row][col] =
        *reinterpret_cast<const float4_t*>(x + (size_t)(m0 + row) * NIN + col);
  }

  float acc[8][8];
  #pragma unroll
  for (int nn = 0; nn < 8; ++nn) {
    float bv = bias[nthr * 8 + nn];
    #pragma unroll
    for (int mm = 0; mm < 8; ++mm) acc[nn][mm] = bv;
  }

  for (int kc = 0; kc < 32; ++kc) {
    __syncthreads();
    #pragma unroll
    for (int r = 0; r < 4; ++r) {
      int f = (t + 256 * r) * 4;
      int n = f >> 3, k0 = f & 7;
      float4_t v = *reinterpret_cast<const float4_t*>(w + (size_t)n * NIN + kc * 8 + k0);
      #pragma unroll
      for (int j = 0; j < 4; ++j) wsT[k0 + j][n] = v[j];
    }
    __syncthreads();
    #pragma unroll
    for (int kp = 0; kp < 8; ++kp) {
      float4_t wv0 = *(const float4_t*)&wsT[kp][nthr * 8];
      float4_t wv1 = *(const float4_t*)&wsT[kp][nthr * 8 + 4];
      #pragma unroll
      for (int mm = 0; mm < 8; ++mm) {
        float xv = xs[mthr * 8 + mm][kc * 8 + kp];
        acc[0][mm] = fmaf(wv0.x, xv, acc[0][mm]);
        acc[1][mm] = fmaf(wv0.y, xv, acc[1][mm]);
        acc[2][mm] = fmaf(wv0.z, xv, acc[2][mm]);
        acc[3][mm] = fmaf(wv0.w, xv, acc[3][mm]);
        acc[4][mm] = fmaf(wv1.x, xv, acc[4][mm]);
        acc[5][mm] = fmaf(wv1.y, xv, acc[5][mm]);
        acc[6][mm] = fmaf(wv1.z, xv, acc[6][mm]);
        acc[7][mm] = fmaf(wv1.w, xv, acc[7][mm]);
      }
    }
  }

  const int n0 = nthr * 8;
  float* dst = (n0 < 256) ? (xplo + n0) : (xphi + (n0 - 256));
  #pragma unroll
  for (int mm = 0; mm < 8; ++mm) {
    int m = m0 + mthr * 8 + mm;
    float4_t o0 = {acc[0][mm], acc[1][mm], acc[2][mm], acc[3][mm]};
    float4_t o1 = {acc[4][mm], acc[5][mm], acc[6][mm], acc[7][mm]};
    *reinterpret_cast<float4_t*>(dst + (size_t)m * 256)     = o0;
    *reinterpret_cast<float4_t*>(dst + (size_t)m * 256 + 4) = o1;
  }
}

// ---------------- Phase B: f32 recurrence, quarter-split, R6 protocol ----------------
// block g: batch b=(g>>5)*8+(g&7) (members share g&7 -> same XCD), quarter q=(g>>3)&3
// owns hidden rows [q*128, +128). thread t: js=t&63 -> rows r0=q*128+js*2, r1=r0+1;
// ks=t>>6 = wave idx -> k-slice [ks*64,+64) (wave-uniform LDS h reads -> broadcast).
// W: w0[16],w1[16] float4 = 128 VGPR. Reduction: pacc LDS (R6-proven). Own-k waves
// (ks>>1==q) compute BEFORE the poll to overlap partner RTT.
__global__ __launch_bounds__(512, 1) void k_recur(
    const float* __restrict__ whh, float* outbuf, float* wsbuf)
{
  __shared__ __align__(16) float hb[2][NHID];
  __shared__ __align__(16) float pacc[8][128];
  const int g = blockIdx.x;
  const int b = (g >> 5) * 8 + (g & 7);
  const int q = (g >> 3) & 3;
  const int t = threadIdx.x;
  const int js = t & 63;
  const int ks = t >> 6;
  const int r0 = q * 128 + js * 2, r1 = r0 + 1;
  const bool ownk = (ks >> 1) == q;                 // k-slice produced by this block

  float4_t w0[16], w1[16];
  #pragma unroll
  for (int i = 0; i < 16; ++i) {
    w0[i] = FL4(whh + (size_t)r0 * NHID + ks * 64 + i * 4);
    w1[i] = FL4(whh + (size_t)r1 * NHID + ks * 64 + i * 4);
  }

  float* xp = ((q < 2) ? (outbuf + q * 128) : (wsbuf + (q - 2) * 128))
              + (size_t)b * NT * 256 + t;           // used by t<128 only
  float xq0 = 0.f, xq1 = 0.f;
  if (t < 128) { xq0 = xp[0]; xq1 = xp[256]; }

  hb[0][t] = 0.0f;                                  // h_{-1} = 0
  __syncthreads();

  for (int s = 0; s < NT; ++s) {
    float* hbc = hb[s & 1];
    float* hbn = hb[(s & 1) ^ 1];

    float4_t a0 = {0.f,0.f,0.f,0.f}, a1 = {0.f,0.f,0.f,0.f};
    float4_t b0 = {0.f,0.f,0.f,0.f}, b1 = {0.f,0.f,0.f,0.f};

    if (ownk) {                                     // own rows ready since last finalize
      const float4_t* h4 = (const float4_t*)&hbc[ks * 64];
      #pragma unroll
      for (int i = 0; i < 16; i += 2) {
        float4_t hA = h4[i], hB = h4[i + 1];
        a0 += w0[i] * hA;  a1 += w0[i + 1] * hB;
        b0 += w1[i] * hA;  b1 += w1[i + 1] * hB;
      }
    }

    if (s > 0) {                                    // R6-proven: poll -> barrier -> read
      if (t < 3) {
        const int pq = (q + 1 + t) & 3;
        while (LOADA(&g_flag[b * 64 + pq * 16]) < s) {}
      }
      __syncthreads();
      if (t < 384) {
        const int prow = (q * 128 + 128 + t) & 511;
        hbc[prow] = LOADA(&g_hpub[b][(s - 1) & 1][prow]);
      }
      __syncthreads();
    }

    if (!ownk) {                                    // partner-k (zeros at s==0: correct)
      const float4_t* h4 = (const float4_t*)&hbc[ks * 64];
      #pragma unroll
      for (int i = 0; i < 16; i += 2) {
        float4_t hA = h4[i], hB = h4[i + 1];
        a0 += w0[i] * hA;  a1 += w0[i + 1] * hB;
        b0 += w1[i] * hA;  b1 += w1[i + 1] * hB;
      }
    }

    float4_t av = a0 + a1, bv = b0 + b1;
    pacc[ks][js * 2]     = (av.x + av.y) + (av.z + av.w);
    pacc[ks][js * 2 + 1] = (bv.x + bv.y) + (bv.z + bv.w);
    __syncthreads();                                // pacc complete

    if (t < 128) {                                  // finalize row q*128+t
      float sum = pacc[0][t];
      #pragma unroll
      for (int k2 = 1; k2 < 8; ++k2) sum += pacc[k2][t];
      float h = tanhf(sum + xq0);
      hbn[q * 128 + t] = h;                         // own rows for next step
      STOREA(&g_hpub[b][s & 1][q * 128 + t], h);    // publish (drained by next barrier)
      xp[(size_t)s * 256] = h;                      // hs for phase C
      xq0 = xq1;
      if (s + 2 < NT) xq1 = xp[(size_t)(s + 2) * 256];
    }
    __syncthreads();                                // vmcnt(0): publishes visible; hbn ready
    if (t == 0) STOREA(&g_flag[b * 64 + q * 16], s + 1);
  }
}

// ---------------- Phase C: out-projection (f16 dot2, f32 out, in-place; proven) ------------
__global__ __launch_bounds__(256) void k_outproj(
    const float* hlo, const float* hhi, const float* __restrict__ w,
    const float* __restrict__ bias, float* out)
{
  __shared__ half2_t xs[32][258];
  __shared__ half2_t ws[256][19];
  const int t = threadIdx.x;
  const int m0 = blockIdx.x * 32;
  const int nthr = t >> 2;
  const int mthr = t & 3;

  #pragma unroll
  for (int r = 0; r < 16; ++r) {
    int f = (t + 256 * r) * 4;
    int row = f >> 9, col = f & 511;
    const float* src = (col < 256) ? (hlo + (size_t)(m0 + row) * 256 + col)
                                   : (hhi + (size_t)(m0 + row) * 256 + (col - 256));
    float4_t v = *reinterpret_cast<const float4_t*>(src);
    xs[row][(col >> 1)]     = half2_t{(f16)v.x, (f16)v.y};
    xs[row][(col >> 1) + 1] = half2_t{(f16)v.z, (f16)v.w};
  }

  float acc[4][8];
  #pragma unroll
  for (int nn = 0; nn < 4; ++nn) {
    float bv = bias[nthr * 4 + nn];
    #pragma unroll
    for (int mm = 0; mm < 8; ++mm) acc[nn][mm] = bv;
  }

  for (int kc = 0; kc < 16; ++kc) {
    __syncthreads();
    #pragma unroll
    for (int r = 0; r < 8; ++r) {
      int f = (t + 256 * r) * 4;
      int row = f >> 5, col = f & 31;
      float4_t v = *reinterpret_cast<const float4_t*>(w + (size_t)row * NHID + kc * 32 + col);
      ws[row][(col >> 1)]     = half2_t{(f16)v.x, (f16)v.y};
      ws[row][(col >> 1) + 1] = half2_t{(f16)v.z, (f16)v.w};
    }
    __syncthreads();
    #pragma unroll
    for (int kp = 0; kp < 16; ++kp) {
      half2_t wv[4], xv[8];
      #pragma unroll
      for (int nn = 0; nn < 4; ++nn) wv[nn] = ws[nthr * 4 + nn][kp];
      #pragma unroll
      for (int mm = 0; mm < 8; ++mm) xv[mm] = xs[mthr * 8 + mm][kc * 16 + kp];
      #pragma unroll
      for (int nn = 0; nn < 4; ++nn)
        #pragma unroll
        for (int mm = 0; mm < 8; ++mm)
          acc[nn][mm] = fdot2f(wv[nn], xv[mm], acc[nn][mm]);
    }
  }

  #pragma unroll
  for (int mm = 0; mm < 8; ++mm) {
    int m = m0 + mthr * 8 + mm;
    float4_t o = {acc[0][mm], acc[1][mm], acc[2][mm], acc[3][mm]};
    *reinterpret_cast<float4_t*>(out + (size_t)m * NOUT + nthr * 4) = o;
  }
}

extern "C" void kernel_launch(void* const* d_in, const int* in_sizes, int n_in,
                              void* d_out, int out_size, void* d_ws, size_t ws_size,
                              hipStream_t stream) {
  (void)in_sizes; (void)n_in; (void)ws_size; (void)out_size;
  const float* x     = (const float*)d_in[0];
  const float* w_ih  = (const float*)d_in[1];
  const float* w_hh  = (const float*)d_in[2];
  const float* b_h   = (const float*)d_in[3];
  const float* w_out = (const float*)d_in[4];
  const float* b_out = (const float*)d_in[5];

  float* outb = (float*)d_out;   // xp cols 0..255  -> h rows 0..255  -> y   (134 MB)
  float* wsb  = (float*)d_ws;    // xp cols 256..511 -> h rows 256..511     (134 MB, proven)

  k_zero   <<<16, 256, 0, stream>>>();
  k_inproj <<<(NBATCH * NT) / 32, 256, 0, stream>>>(x, w_ih, b_h, outb, wsb);
  k_recur  <<<256, 512, 0, stream>>>(w_hh, outb, wsb);
  k_outproj<<<(NBATCH * NT) / 32, 256, 0, stream>>>(outb, wsb, w_out, b_out, outb);
}